// Round 1
// baseline (308.156 us; speedup 1.0000x reference)
//
#include <hip/hip_runtime.h>
#include <stdint.h>

// Problem constants
#define B_ 16
#define T_ 512
#define F_ 32
#define CI_ 128
#define CO_ 128
#define K_ 3
#define LPAD 4            // DIL*(K-1)
#define TM 128            // output rows per block tile
#define XROWS (TM + LPAD) // 132 staged x rows (halo for taps)
#define PITCH 136         // bf16 elems per LDS row: 128 data + 8 pad (272B, 16B-aligned, bank-rotation 4 -> 2-way = free)
#define WT_TILE (CO_ * PITCH) // elements per (f,k) packed weight tile

typedef __attribute__((ext_vector_type(8))) __bf16 bf16x8;
typedef __attribute__((ext_vector_type(4))) float f32x4;

__device__ __forceinline__ uint16_t f2bf(float x) {
  // round-to-nearest-even fp32 -> bf16
  uint32_t u = __builtin_bit_cast(uint32_t, x);
  u += 0x7fffu + ((u >> 16) & 1u);
  return (uint16_t)(u >> 16);
}

// Repack w[f][o][i][k] fp32 -> wt[f][k][o][PITCH] bf16 (rows padded to 272B so
// global_load_lds' lane-contiguous LDS dest lands in padded layout directly).
__global__ __launch_bounds__(256) void repack_w(const float* __restrict__ w,
                                                uint16_t* __restrict__ wt) {
  int idx = blockIdx.x * 256 + threadIdx.x;      // one thread per 4-elem chunk
  int c4 = idx % 34;                             // 34 chunks of 4 = 136 (incl pad)
  int rest = idx / 34;
  int o = rest & (CO_ - 1);
  rest >>= 7;
  int k = rest % 3;
  int f = rest / 3;
  if (f >= F_) return;
  uint16_t h[4];
#pragma unroll
  for (int j = 0; j < 4; ++j) {
    int i = c4 * 4 + j;
    float v = (i < CI_) ? w[(((size_t)(f * CO_ + o)) * CI_ + i) * K_ + k] : 0.f;
    h[j] = f2bf(v);
  }
  uint2 pk;
  pk.x = (uint32_t)h[0] | ((uint32_t)h[1] << 16);
  pk.y = (uint32_t)h[2] | ((uint32_t)h[3] << 16);
  *(uint2*)&wt[((size_t)(f * 3 + k) * CO_ + o) * PITCH + c4 * 4] = pk;
}

// Main fused conv kernel. Block = (f, b, t0): 128x128 output tile, K-loop over 3 taps.
template <bool PACKED>
__global__ __launch_bounds__(256, 2) void conv_main(
    const float* __restrict__ x, const uint16_t* __restrict__ wt,
    const float* __restrict__ wraw, const float* __restrict__ bias,
    float* __restrict__ y) {
  __shared__ __align__(16) uint16_t xs[XROWS * PITCH]; // 35,904 B
  __shared__ __align__(16) uint16_t wsm[CO_ * PITCH];  // 34,816 B  (total 70.7KB -> 2 blocks/CU)

  const int bid = blockIdx.x;
  const int f = bid >> 6;         // 0..31
  const int mt = bid & 63;
  const int b = mt >> 2;          // 0..15
  const int t0 = (mt & 3) << 7;   // 0,128,256,384 (tiles never cross batch)

  const int tid = threadIdx.x;
  const int lane = tid & 63;
  const int wave = tid >> 6;
  const int wm = wave >> 1;       // wave tile row (0..1)
  const int wn = wave & 1;        // wave tile col (0..1)
  const int l15 = lane & 15;
  const int quad = lane >> 4;

  // Init accumulators with bias (C/D layout: col = lane&15, row = quad*4+reg;
  // all 4 regs share the same col -> same bias value).
  f32x4 acc[4][4];
#pragma unroll
  for (int fn = 0; fn < 4; ++fn) {
    float bv = bias[f * CO_ + wn * 64 + fn * 16 + l15];
#pragma unroll
    for (int fm = 0; fm < 4; ++fm) acc[fm][fn] = (f32x4){bv, bv, bv, bv};
  }

  // Stage x window [t0-4, t0+128) for this (b,f) into LDS as bf16 (once; shared by all taps).
  {
    const float* xb = x + ((size_t)b * T_ * F_ + f) * CI_;
    for (int idx = tid; idx < XROWS * 32; idx += 256) {
      int row = idx >> 5, c4 = idx & 31;
      int t = t0 - LPAD + row;
      float4 v = make_float4(0.f, 0.f, 0.f, 0.f);
      if (t >= 0) v = *(const float4*)(xb + (size_t)t * (F_ * CI_) + c4 * 4);
      uint2 pk;
      pk.x = (uint32_t)f2bf(v.x) | ((uint32_t)f2bf(v.y) << 16);
      pk.y = (uint32_t)f2bf(v.z) | ((uint32_t)f2bf(v.w) << 16);
      *(uint2*)&xs[row * PITCH + c4 * 4] = pk;
    }
  }

#pragma unroll 1
  for (int k = 0; k < K_; ++k) {
    // Stage W(f,k) -> LDS (B^T layout: wsm[o][i])
    if constexpr (PACKED) {
      const uint16_t* wk = wt + (size_t)(f * 3 + k) * WT_TILE;
      // 34,816 B = 34 wave-instructions of 1KB (64 lanes x 16B, lane-contiguous LDS dest)
      for (int c = wave; c < 34; c += 4) {
        __builtin_amdgcn_global_load_lds(
            (const __attribute__((address_space(1))) uint32_t*)(wk + c * 512 + lane * 8),
            (__attribute__((address_space(3))) uint32_t*)&wsm[c * 512], 16, 0, 0);
      }
    } else {
      // fallback: gather from original layout (stride-3 over i)
      for (int idx = tid; idx < CO_ * 32; idx += 256) {
        int o = idx >> 5, c4 = idx & 31;
        const float* ws0 = wraw + (((size_t)(f * CO_ + o)) * CI_ + c4 * 4) * K_ + k;
        uint2 pk;
        pk.x = (uint32_t)f2bf(ws0[0]) | ((uint32_t)f2bf(ws0[3]) << 16);
        pk.y = (uint32_t)f2bf(ws0[6]) | ((uint32_t)f2bf(ws0[9]) << 16);
        *(uint2*)&wsm[o * PITCH + c4 * 4] = pk;
      }
    }
    __syncthreads(); // also covers xs staging on k=0; compiler drains vmcnt before s_barrier

    // 4 kappa-steps of K=32 over CI; tap k shifts A rows by 2k within the staged window
    const int xr0 = wm * 64 + l15 + 2 * k;
    const int wr0 = wn * 64 + l15;
    const int kq = quad * 8;
#pragma unroll
    for (int i0 = 0; i0 < CI_; i0 += 32) {
      bf16x8 av[4], bv[4];
#pragma unroll
      for (int fm = 0; fm < 4; ++fm)
        av[fm] = *(const bf16x8*)&xs[(xr0 + fm * 16) * PITCH + i0 + kq];
#pragma unroll
      for (int fn = 0; fn < 4; ++fn)
        bv[fn] = *(const bf16x8*)&wsm[(wr0 + fn * 16) * PITCH + i0 + kq];
#pragma unroll
      for (int fm = 0; fm < 4; ++fm)
#pragma unroll
        for (int fn = 0; fn < 4; ++fn)
          acc[fm][fn] = __builtin_amdgcn_mfma_f32_16x16x32_bf16(av[fm], bv[fn],
                                                                acc[fm][fn], 0, 0, 0);
    }
    if (k < K_ - 1) __syncthreads(); // before overwriting wsm
  }

  // Epilogue: D[row][col], row = quad*4 + r, col = lane&15 (m89-verified mapping)
  float* yb = y + ((size_t)b * T_ * F_ + f) * CO_;
#pragma unroll
  for (int fm = 0; fm < 4; ++fm) {
    int r0 = t0 + wm * 64 + fm * 16 + quad * 4;
#pragma unroll
    for (int fn = 0; fn < 4; ++fn) {
      int col = wn * 64 + fn * 16 + l15;
#pragma unroll
      for (int r = 0; r < 4; ++r)
        yb[(size_t)(r0 + r) * (F_ * CO_) + col] = acc[fm][fn][r];
    }
  }
}

extern "C" void kernel_launch(void* const* d_in, const int* in_sizes, int n_in,
                              void* d_out, int out_size, void* d_ws, size_t ws_size,
                              hipStream_t stream) {
  const float* x = (const float*)d_in[0];
  const float* w = (const float*)d_in[1];
  const float* bias = (const float*)d_in[2];
  float* y = (float*)d_out;

  const size_t wt_bytes = (size_t)F_ * 3 * WT_TILE * sizeof(uint16_t); // ~3.2 MiB
  const int main_blocks = F_ * B_ * (T_ / TM); // 32*16*4 = 2048

  if (ws_size >= wt_bytes) {
    uint16_t* wtp = (uint16_t*)d_ws;
    const int total = F_ * 3 * CO_ * 34;
    repack_w<<<(total + 255) / 256, 256, 0, stream>>>(w, wtp);
    conv_main<true><<<main_blocks, 256, 0, stream>>>(x, wtp, w, bias, y);
  } else {
    conv_main<false><<<main_blocks, 256, 0, stream>>>(x, (const uint16_t*)nullptr, w, bias, y);
  }
}

// Round 2
// 278.941 us; speedup vs baseline: 1.1047x; 1.1047x over previous
//
#include <hip/hip_runtime.h>
#include <stdint.h>

// Problem constants
#define B_ 16
#define T_ 512
#define F_ 32
#define CI_ 128
#define CO_ 128
#define K_ 3
#define LPAD 4              // DIL*(K-1)
#define TM 64               // output rows per block tile
#define XROWS (TM + LPAD)   // 68 staged x rows (halo for taps)
#define XPITCH 136          // bf16/row: 128 data + 8 pad (272B, 16B-aligned)
#define WPITCH 32           // w chunk row = 32 bf16, no pad (uniform 8/bank-group for b128)
#define CHUNK_ELEMS (CO_ * WPITCH) // 4096 elems = 8 KB per (tap,kstep) chunk
#define NCHUNK 12           // 3 taps * 4 ksteps

typedef __attribute__((ext_vector_type(8))) __bf16 bf16x8;
typedef __attribute__((ext_vector_type(4))) float f32x4;

__device__ __forceinline__ uint16_t f2bf(float x) {
  // round-to-nearest-even fp32 -> bf16
  uint32_t u = __builtin_bit_cast(uint32_t, x);
  u += 0x7fffu + ((u >> 16) & 1u);
  return (uint16_t)(u >> 16);
}

// Coalesced repack: w[f][o][i][k] fp32 -> wt2[f][tap*4+kstep][o][32] bf16.
// Thread <-> (f,o,i): reads 12 contiguous bytes, writes 3 bf16 (one per tap).
__global__ __launch_bounds__(256) void repack_w(const float* __restrict__ w,
                                                uint16_t* __restrict__ wt2) {
  int idx = blockIdx.x * 256 + threadIdx.x; // (f*CO+o)*CI + i ; grid sized exactly
  int i = idx & (CI_ - 1);
  int fo = idx >> 7;
  int o = fo & (CO_ - 1);
  int f = fo >> 7;
  const float* src = w + (size_t)idx * K_;
  float a0 = src[0], a1 = src[1], a2 = src[2];
  size_t base = ((size_t)f * NCHUNK + (i >> 5)) * CHUNK_ELEMS + o * WPITCH + (i & 31);
  wt2[base] = f2bf(a0);                      // tap 0, kstep i>>5
  wt2[base + 4 * (size_t)CHUNK_ELEMS] = f2bf(a1); // tap 1
  wt2[base + 8 * (size_t)CHUNK_ELEMS] = f2bf(a2); // tap 2
}

// Main fused conv kernel. Block = (f, b, t0): 64x128 output tile.
// K-loop = 12 chunks (3 taps x 4 ksteps of K=32), double-buffered w prefetch.
template <bool PACKED>
__global__ __launch_bounds__(256, 4) void conv_main(
    const float* __restrict__ x, const uint16_t* __restrict__ wt2,
    const float* __restrict__ wraw, const float* __restrict__ bias,
    float* __restrict__ y) {
  __shared__ __align__(16) uint16_t xs[XROWS * XPITCH];   // 18,496 B
  __shared__ __align__(16) uint16_t wbuf[2][CHUNK_ELEMS]; // 16,384 B -> total 34.9 KB, 4 blocks/CU

  const int bid = blockIdx.x;
  const int f = bid >> 7;        // 0..31 (consecutive bids share f -> wt2 hot in L2)
  const int mt = bid & 127;
  const int b = mt >> 3;         // 0..15
  const int t0 = (mt & 7) << 6;  // 0..448 (tiles never cross batch)

  const int tid = threadIdx.x;
  const int lane = tid & 63;
  const int wave = tid >> 6;
  const int wm = wave >> 1;      // 2x2 waves of 32(row) x 64(col)
  const int wn = wave & 1;
  const int l15 = lane & 15;
  const int quad = lane >> 4;

  // Bias-init accumulators (C/D layout: col = lane&15, row = quad*4+reg).
  f32x4 acc[2][4];
#pragma unroll
  for (int fn = 0; fn < 4; ++fn) {
    float bv = bias[f * CO_ + wn * 64 + fn * 16 + l15];
#pragma unroll
    for (int fm = 0; fm < 2; ++fm) acc[fm][fn] = (f32x4){bv, bv, bv, bv};
  }

  auto issue_chunk = [&](int idx, int buf) { // async global->LDS, 8 x 1KB wave-instrs
    const uint16_t* src = wt2 + ((size_t)(f * NCHUNK + idx)) * CHUNK_ELEMS;
    for (int c = wave; c < 8; c += 4)
      __builtin_amdgcn_global_load_lds(
          (const __attribute__((address_space(1))) uint32_t*)(src + c * 512 + lane * 8),
          (__attribute__((address_space(3))) uint32_t*)&wbuf[buf][c * 512], 16, 0, 0);
  };
  auto gather_chunk = [&](int idx, int buf) { // fallback: strided gather from raw w
    int tap = idx >> 2, i0 = (idx & 3) << 5;
    for (int e = tid; e < CHUNK_ELEMS; e += 256) {
      int o = e >> 5, i = i0 + (e & 31);
      wbuf[buf][e] = f2bf(wraw[(((size_t)(f * CO_ + o)) * CI_ + i) * K_ + tap]);
    }
  };

  if constexpr (PACKED) issue_chunk(0, 0); // flies during x staging

  // Stage x window [t0-4, t0+64) as bf16 into LDS (shared by all taps).
  {
    const float* xb = x + ((size_t)b * T_ * F_ + f) * CI_;
    for (int idx = tid; idx < XROWS * 32; idx += 256) {
      int row = idx >> 5, c4 = idx & 31;
      int t = t0 - LPAD + row;
      float4 v = make_float4(0.f, 0.f, 0.f, 0.f);
      if (t >= 0) v = *(const float4*)(xb + (size_t)t * (F_ * CI_) + c4 * 4);
      uint2 pk;
      pk.x = (uint32_t)f2bf(v.x) | ((uint32_t)f2bf(v.y) << 16);
      pk.y = (uint32_t)f2bf(v.z) | ((uint32_t)f2bf(v.w) << 16);
      *(uint2*)&xs[row * XPITCH + c4 * 4] = pk;
    }
  }
  if constexpr (!PACKED) gather_chunk(0, 0);
  __syncthreads(); // drains x stores + chunk0 glds

#pragma unroll 1
  for (int idx = 0; idx < NCHUNK; ++idx) {
    const int cur = idx & 1;
    if (idx + 1 < NCHUNK) { // prefetch next chunk into the other buffer
      if constexpr (PACKED) issue_chunk(idx + 1, cur ^ 1);
      else gather_chunk(idx + 1, cur ^ 1);
    }

    const int tap = idx >> 2;
    const int kq0 = (idx & 3) * 32 + quad * 8;
    const int xr0 = wm * 32 + l15 + 2 * tap; // tap shifts A rows by DIL*k
    bf16x8 av[2], bv[4];
#pragma unroll
    for (int fm = 0; fm < 2; ++fm)
      av[fm] = *(const bf16x8*)&xs[(xr0 + fm * 16) * XPITCH + kq0];
#pragma unroll
    for (int fn = 0; fn < 4; ++fn)
      bv[fn] = *(const bf16x8*)&wbuf[cur][(wn * 64 + fn * 16 + l15) * WPITCH + quad * 8];
#pragma unroll
    for (int fm = 0; fm < 2; ++fm)
#pragma unroll
      for (int fn = 0; fn < 4; ++fn)
        acc[fm][fn] = __builtin_amdgcn_mfma_f32_16x16x32_bf16(av[fm], bv[fn],
                                                              acc[fm][fn], 0, 0, 0);
    if (idx + 1 < NCHUNK) __syncthreads(); // guards buf reuse; drains prefetch
  }

  // Epilogue: D[row][col], row = quad*4 + r, col = lane&15 (verified in R1)
  float* yb = y + ((size_t)b * T_ * F_ + f) * CO_;
#pragma unroll
  for (int fm = 0; fm < 2; ++fm) {
    int r0 = t0 + wm * 32 + fm * 16 + quad * 4;
#pragma unroll
    for (int fn = 0; fn < 4; ++fn) {
      int col = wn * 64 + fn * 16 + l15;
#pragma unroll
      for (int r = 0; r < 4; ++r)
        yb[(size_t)(r0 + r) * (F_ * CO_) + col] = acc[fm][fn][r];
    }
  }
}

extern "C" void kernel_launch(void* const* d_in, const int* in_sizes, int n_in,
                              void* d_out, int out_size, void* d_ws, size_t ws_size,
                              hipStream_t stream) {
  const float* x = (const float*)d_in[0];
  const float* w = (const float*)d_in[1];
  const float* bias = (const float*)d_in[2];
  float* y = (float*)d_out;

  const size_t wt2_bytes = (size_t)F_ * NCHUNK * CHUNK_ELEMS * sizeof(uint16_t); // 3.0 MiB
  const int main_blocks = F_ * B_ * (T_ / TM); // 32*16*8 = 4096

  if (ws_size >= wt2_bytes) {
    uint16_t* wt2 = (uint16_t*)d_ws;
    const int total = F_ * CO_ * CI_; // 524288 threads, exact multiple of 256
    repack_w<<<total / 256, 256, 0, stream>>>(w, wt2);
    conv_main<true><<<main_blocks, 256, 0, stream>>>(x, wt2, w, bias, y);
  } else {
    conv_main<false><<<main_blocks, 256, 0, stream>>>(x, (const uint16_t*)nullptr, w, bias, y);
  }
}

// Round 3
// 267.426 us; speedup vs baseline: 1.1523x; 1.0431x over previous
//
#include <hip/hip_runtime.h>
#include <stdint.h>

// Problem constants
#define B_ 16
#define T_ 512
#define F_ 32
#define CI_ 128
#define CO_ 128
#define K_ 3
#define LPAD 4              // DIL*(K-1)
#define TM 64               // output rows per tile
#define XROWS (TM + LPAD)   // 68 staged x rows
#define XPITCH 136          // bf16/row: 128 data + 8 pad (272B; row bank-step 4 -> 2-way = free)
#define WPITCH 32
#define CHUNK_ELEMS (CO_ * WPITCH) // 4096 elems per (tap,kstep) chunk
#define NCHUNK 12           // 3 taps * 4 ksteps of K=32
#define NXV 5               // ceil(68*32 / 512) float4 per thread

typedef __attribute__((ext_vector_type(8))) __bf16 bf16x8;
typedef __attribute__((ext_vector_type(4))) float f32x4;

__device__ __forceinline__ uint16_t f2bf(float x) {
  uint32_t u = __builtin_bit_cast(uint32_t, x);
  u += 0x7fffu + ((u >> 16) & 1u);
  return (uint16_t)(u >> 16);
}

// Coalesced repack: w[f][o][i][k] fp32 -> wt2[f][tap*4+kstep][o][32] bf16.
__global__ __launch_bounds__(256) void repack_w(const float* __restrict__ w,
                                                uint16_t* __restrict__ wt2) {
  int idx = blockIdx.x * 256 + threadIdx.x; // (f*CO+o)*CI + i
  int i = idx & (CI_ - 1);
  int fo = idx >> 7;
  int o = fo & (CO_ - 1);
  int f = fo >> 7;
  const float* src = w + (size_t)idx * K_;
  float a0 = src[0], a1 = src[1], a2 = src[2];
  size_t base = ((size_t)f * NCHUNK + (i >> 5)) * CHUNK_ELEMS + o * WPITCH + (i & 31);
  wt2[base] = f2bf(a0);
  wt2[base + 4 * (size_t)CHUNK_ELEMS] = f2bf(a1);
  wt2[base + 8 * (size_t)CHUNK_ELEMS] = f2bf(a2);
}

// Block = (f, b), 512 threads = 8 waves, each wave owns 16 output cols with its
// W fragments pinned in 48 VGPRs. Sweeps the 8 t-tiles of 64 rows; xs is the
// only LDS (18.5 KB) -> 2 blocks/CU, 16 waves/CU; x prefetched 2 tiles ahead
// into registers; only 2 barriers per tile.
template <bool PACKED>
__global__ __launch_bounds__(512, 4) void conv_main(
    const float* __restrict__ x, const uint16_t* __restrict__ wt2,
    const float* __restrict__ wraw, const float* __restrict__ bias,
    float* __restrict__ y) {
  __shared__ __align__(16) uint16_t xs[XROWS * XPITCH]; // 18,496 B

  const int bid = blockIdx.x;
  const int f = bid >> 4;   // 0..31
  const int b = bid & 15;   // 0..15

  const int tid = threadIdx.x;
  const int lane = tid & 63;
  const int wave = tid >> 6;   // 0..7 -> col group
  const int l15 = lane & 15;
  const int quad = lane >> 4;
  const int co0 = wave * 16;

  // ---- W fragments -> registers (once per block) ----
  bf16x8 wreg[NCHUNK];
  if constexpr (PACKED) {
    const uint16_t* wp = wt2 + (size_t)f * NCHUNK * CHUNK_ELEMS + (co0 + l15) * WPITCH + quad * 8;
#pragma unroll
    for (int c = 0; c < NCHUNK; ++c)
      wreg[c] = *(const bf16x8*)(wp + c * CHUNK_ELEMS);
  } else {
#pragma unroll
    for (int c = 0; c < NCHUNK; ++c) {
      int tap = c >> 2, i0 = (c & 3) * 32 + quad * 8;
      const float* ws = wraw + (((size_t)(f * CO_ + co0 + l15)) * CI_ + i0) * K_ + tap;
      union { bf16x8 v; uint16_t h[8]; } u;
#pragma unroll
      for (int j = 0; j < 8; ++j) u.h[j] = f2bf(ws[j * K_]);
      wreg[c] = u.v;
    }
  }
  const float bv = bias[f * CO_ + co0 + l15];

  const float* xb = x + ((size_t)b * T_ * F_ + f) * CI_;
  float4 xr[NXV];

  auto load_x = [&](int t0) { // issue global loads for tile window into regs
#pragma unroll
    for (int it = 0; it < NXV; ++it) {
      int idx = tid + it * 512;
      if (idx < XROWS * 32) {
        int row = idx >> 5, c4 = idx & 31;
        int t = t0 - LPAD + row;
        xr[it] = (t >= 0) ? *(const float4*)(xb + (size_t)t * (F_ * CI_) + c4 * 4)
                          : make_float4(0.f, 0.f, 0.f, 0.f);
      }
    }
  };
  auto store_x = [&]() { // cvt + write staged regs into xs
#pragma unroll
    for (int it = 0; it < NXV; ++it) {
      int idx = tid + it * 512;
      if (idx < XROWS * 32) {
        int row = idx >> 5, c4 = idx & 31;
        uint2 pk;
        pk.x = (uint32_t)f2bf(xr[it].x) | ((uint32_t)f2bf(xr[it].y) << 16);
        pk.y = (uint32_t)f2bf(xr[it].z) | ((uint32_t)f2bf(xr[it].w) << 16);
        *(uint2*)&xs[row * XPITCH + c4 * 4] = pk;
      }
    }
  };

  load_x(0);
  store_x();
  load_x(TM); // prefetch tile 1
  __syncthreads();

  const int abase = l15 * XPITCH + quad * 8; // elem offset; rest is static imms

#pragma unroll 1
  for (int j = 0; j < 8; ++j) {
    const int t0 = j * TM;
    f32x4 acc[4];
#pragma unroll
    for (int fm = 0; fm < 4; ++fm) acc[fm] = (f32x4){bv, bv, bv, bv};

#pragma unroll
    for (int c = 0; c < NCHUNK; ++c) {
      const int tap = c >> 2, ks = c & 3;
#pragma unroll
      for (int fm = 0; fm < 4; ++fm) {
        bf16x8 av = *(const bf16x8*)&xs[abase + (2 * tap + fm * 16) * XPITCH + ks * 32];
        acc[fm] = __builtin_amdgcn_mfma_f32_16x16x32_bf16(av, wreg[c], acc[fm], 0, 0, 0);
      }
    }

    // Epilogue: D row = quad*4 + r, col = l15 (verified R1/R2)
    float* yb = y + (((size_t)b * T_ + t0) * F_ + f) * CO_ + co0;
#pragma unroll
    for (int fm = 0; fm < 4; ++fm)
#pragma unroll
      for (int r = 0; r < 4; ++r)
        yb[(size_t)(fm * 16 + quad * 4 + r) * (F_ * CO_) + l15] = acc[fm][r];

    if (j < 7) {
      __syncthreads();            // all waves done reading xs
      store_x();                  // stage tile j+1 (regs loaded a phase ago)
      if (j < 6) load_x((j + 2) * TM); // refill prefetch regs
      __syncthreads();            // xs ready
    }
  }
}

extern "C" void kernel_launch(void* const* d_in, const int* in_sizes, int n_in,
                              void* d_out, int out_size, void* d_ws, size_t ws_size,
                              hipStream_t stream) {
  const float* x = (const float*)d_in[0];
  const float* w = (const float*)d_in[1];
  const float* bias = (const float*)d_in[2];
  float* y = (float*)d_out;

  const size_t wt2_bytes = (size_t)F_ * NCHUNK * CHUNK_ELEMS * sizeof(uint16_t); // 3.0 MiB
  const int main_blocks = F_ * B_; // 512 blocks = 2 resident/CU

  if (ws_size >= wt2_bytes) {
    uint16_t* wt2 = (uint16_t*)d_ws;
    const int total = F_ * CO_ * CI_; // 524288
    repack_w<<<total / 256, 256, 0, stream>>>(w, wt2);
    conv_main<true><<<main_blocks, 512, 0, stream>>>(x, wt2, w, bias, y);
  } else {
    conv_main<false><<<main_blocks, 512, 0, stream>>>(x, (const uint16_t*)nullptr, w, bias, y);
  }
}